// Round 3
// baseline (122.706 us; speedup 1.0000x reference)
//
#include <hip/hip_runtime.h>

// Problem constants (B=16, C=64, H=64, W=64, K=1024, D=64)
#define HWSZ   4096
#define CCH    64
#define KCB    1024
#define NROW   65536
#define NDTOT  4194304

typedef __attribute__((ext_vector_type(8))) short short8;
typedef __attribute__((ext_vector_type(4))) float f32x4;

__device__ __forceinline__ unsigned short f2bf_rn(float x) {
    union { float f; unsigned u; } v; v.f = x;
    unsigned r = (v.u + 0x7fffu + ((v.u >> 16) & 1u)) >> 16;
    return (unsigned short)r;
}

// ---------- prep: E -> bf16 rows + he2b[k] = 1.0 + 0.5*||e_k||^2 ----------
__global__ __launch_bounds__(256) void vq_prep(const float* __restrict__ E,
                                               unsigned* __restrict__ Ebf,
                                               float* __restrict__ he2b) {
    int k = blockIdx.x * 256 + threadIdx.x;   // 0..1023
    const float4* ep = (const float4*)(E + (size_t)k * 64);
    float s = 0.f;
    #pragma unroll
    for (int c4 = 0; c4 < 16; ++c4) {
        float4 a = ep[c4];
        s += a.x * a.x + a.y * a.y + a.z * a.z + a.w * a.w;
        Ebf[(size_t)k * 32 + 2 * c4 + 0] = (unsigned)f2bf_rn(a.x) | ((unsigned)f2bf_rn(a.y) << 16);
        Ebf[(size_t)k * 32 + 2 * c4 + 1] = (unsigned)f2bf_rn(a.z) | ((unsigned)f2bf_rn(a.w) << 16);
    }
    he2b[k] = 1.0f + 0.5f * s;
}

// ---------- main: MFMA scan + packed argmin + output + loss partial ----------
__global__ __launch_bounds__(256, 4) void vq_mfma(const float* __restrict__ z,
                                                  const float* __restrict__ E,
                                                  const short* __restrict__ Ebf,
                                                  const float* __restrict__ he2g,
                                                  float* __restrict__ out,
                                                  float* __restrict__ partial) {
    __shared__ float zs[64][65];       // zs[c][i] = z_flat[n0+i][c] (pad 65: 2-way-free reads)
    __shared__ float he2s[KCB];
    __shared__ unsigned wpack[4][64];
    __shared__ int   rowidx[64];
    __shared__ float wsum[4];

    const int t   = threadIdx.x;
    const int blk = blockIdx.x;
    const int n0  = blk << 6;
    const int bb  = n0 >> 12;
    const int hw0 = n0 & 4095;
    const float* zb = z + (size_t)bb * CCH * HWSZ + hw0;

    // stage z tile: float4 global loads (coalesced), scalar LDS stores
    #pragma unroll
    for (int q = 0; q < 4; ++q) {
        int fi = q * 256 + t;              // 1024 float4 slots
        int c = fi >> 4, s4 = fi & 15;
        float4 v = *(const float4*)(zb + (size_t)c * HWSZ + s4 * 4);
        zs[c][s4 * 4 + 0] = v.x; zs[c][s4 * 4 + 1] = v.y;
        zs[c][s4 * 4 + 2] = v.z; zs[c][s4 * 4 + 3] = v.w;
    }
    #pragma unroll
    for (int q = 0; q < 4; ++q) he2s[q * 256 + t] = he2g[q * 256 + t];
    __syncthreads();

    const int wid  = t >> 6;
    const int lane = t & 63;
    const int col  = lane & 15;
    const int g    = lane >> 4;

    // A-frags: -z, bf16 by truncation + sign flip (1-2 ops/elem)
    short8 af[4][2];
    #pragma unroll
    for (int rt = 0; rt < 4; ++rt) {
        const int i = rt * 16 + col;
        #pragma unroll
        for (int ch = 0; ch < 2; ++ch) {
            short8 a;
            #pragma unroll
            for (int j = 0; j < 8; ++j) {
                union { float f; unsigned u; } v;
                v.f = zs[ch * 32 + g * 8 + j][i];
                a[j] = (short)((v.u >> 16) ^ 0x8000u);
            }
            af[rt][ch] = a;
        }
    }

    float pk[4][4];                       // running packed (score|idx) minima
    #pragma unroll
    for (int rt = 0; rt < 4; ++rt)
        #pragma unroll
        for (int r = 0; r < 4; ++r) pk[rt][r] = 3.0e38f;

    // B stream: wave's 256-code quarter, 2-deep prefetch
    const short* pB = Ebf + (size_t)(wid * 256 + col) * 64 + g * 8;
    short8 c0 = *(const short8*)(pB);
    short8 c1 = *(const short8*)(pB + 32);
    short8 nx0 = *(const short8*)(pB + 1024);
    short8 nx1 = *(const short8*)(pB + 1024 + 32);

    #pragma unroll
    for (int ct = 0; ct < 16; ++ct) {
        short8 f0 = c0, f1 = c1;
        if (ct < 14) {
            f0 = *(const short8*)(pB + (size_t)(ct + 2) * 1024);
            f1 = *(const short8*)(pB + (size_t)(ct + 2) * 1024 + 32);
        }
        const int code = wid * 256 + ct * 16 + col;     // < 1024, fits 10 bits
        const float h = he2s[code];
        f32x4 hv = {h, h, h, h};
        #pragma unroll
        for (int rt = 0; rt < 4; ++rt) {
            f32x4 acc = __builtin_amdgcn_mfma_f32_16x16x32_bf16(af[rt][0], c0, hv, 0, 0, 0);
            acc = __builtin_amdgcn_mfma_f32_16x16x32_bf16(af[rt][1], c1, acc, 0, 0, 0);
            #pragma unroll
            for (int r = 0; r < 4; ++r) {
                union { float f; unsigned u; } m; m.f = acc[r];   // = 1 + 0.5||e||^2 - z.e  (>0)
                m.u = (m.u & 0xFFFFFC00u) | (unsigned)code;       // v_and_or_b32
                pk[rt][r] = fminf(pk[rt][r], m.f);                // float-min == uint-min (>0)
            }
        }
        c0 = nx0; c1 = nx1; nx0 = f0; nx1 = f1;
    }

    // reduce across the 16 code-columns (lanes within each 16-group)
    #pragma unroll
    for (int rt = 0; rt < 4; ++rt) {
        #pragma unroll
        for (int r = 0; r < 4; ++r) {
            float d = pk[rt][r];
            #pragma unroll
            for (int mask = 1; mask < 16; mask <<= 1)
                d = fminf(d, __shfl_xor(d, mask, 64));
            if (col == 0) {
                union { float f; unsigned u; } b; b.f = d;
                wpack[wid][rt * 16 + g * 4 + r] = b.u;
            }
        }
    }
    __syncthreads();

    if (t < 64) {   // cross-wave min (positive floats: uint compare == float compare)
        unsigned u0 = wpack[0][t], u1 = wpack[1][t], u2 = wpack[2][t], u3 = wpack[3][t];
        unsigned m01 = u0 < u1 ? u0 : u1;
        unsigned m23 = u2 < u3 ? u2 : u3;
        unsigned m = m01 < m23 ? m01 : m23;
        rowidx[t] = (int)(m & 1023u);
    }
    __syncthreads();

    // ---- output = E rows (== z + (q - z) to 1 ulp), float4 stores + loss ----
    float lsum = 0.f;
    const int d0i = (t & 15) * 4;
    const int r0  = t >> 4;
    float* ob = out + (size_t)n0 * 64;
    #pragma unroll
    for (int jj = 0; jj < 4; ++jj) {
        int nl = r0 + 16 * jj;
        int k  = rowidx[nl];                                // wave-uniform per 16 lanes
        float4 qv = *(const float4*)(E + (size_t)k * 64 + d0i);
        float z0 = zs[d0i + 0][nl], z1 = zs[d0i + 1][nl];
        float z2 = zs[d0i + 2][nl], z3 = zs[d0i + 3][nl];
        float e0 = qv.x - z0, e1 = qv.y - z1, e2 = qv.z - z2, e3 = qv.w - z3;
        lsum += e0 * e0 + e1 * e1 + e2 * e2 + e3 * e3;
        *(float4*)(ob + (size_t)nl * 64 + d0i) = qv;
    }

    #pragma unroll
    for (int off = 32; off >= 1; off >>= 1) lsum += __shfl_down(lsum, off, 64);
    if (lane == 0) wsum[wid] = lsum;
    __syncthreads();
    if (t == 0) partial[blk] = (wsum[0] + wsum[1]) + (wsum[2] + wsum[3]);
}

// ---------- fallback fp32 path (round-1, correctness-proven) ----------
__global__ __launch_bounds__(64) void vq_init(float* out) {
    if (threadIdx.x == 0) { out[NDTOT] = 0.0f; out[NDTOT + 1] = 0.0f; }
}

__global__ __launch_bounds__(256, 4) void vq_main_fp32(const float* __restrict__ z,
                                                       const float* __restrict__ E,
                                                       float* __restrict__ out,
                                                       float* __restrict__ partial) {
    __shared__ float zs[64][65];
    __shared__ float e2s[KCB];
    __shared__ float wmin[4][64];
    __shared__ int   widx[4][64];
    __shared__ int   rowidx[64];
    __shared__ float wsum[4];

    const int t   = threadIdx.x;
    const int blk = blockIdx.x;
    const int n0  = blk << 6;
    const int bb  = n0 >> 12;
    const int hw0 = n0 & 4095;
    const float* zb = z + (size_t)bb * CCH * HWSZ + hw0;

    #pragma unroll
    for (int j = 0; j < 16; ++j) {
        int f = t + 256 * j;
        int c = f >> 6, i = f & 63;
        zs[c][i] = zb[(size_t)c * HWSZ + i];
    }
    for (int q = t; q < KCB; q += 256) {
        const float4* ep = (const float4*)(E + (size_t)q * 64);
        float s0 = 0.f;
        #pragma unroll
        for (int c4 = 0; c4 < 16; ++c4) {
            float4 a = ep[c4];
            s0 += a.x * a.x + a.y * a.y + a.z * a.z + a.w * a.w;
        }
        e2s[q] = s0;
    }
    __syncthreads();

    const int i   = t & 63;
    const int wid = t >> 6;
    float zr[64];
    #pragma unroll
    for (int c = 0; c < 64; ++c) zr[c] = zs[c][i];

    float best = 3.4e38f;
    int   bi = 0;
    const int k0 = wid << 8;
    const float* Ew = E + (size_t)k0 * 64;
    for (int kk = 0; kk < 256; ++kk) {
        const float4* ek = (const float4*)(Ew + (size_t)kk * 64);
        float d0 = 0.f, d1 = 0.f, d2 = 0.f, d3 = 0.f;
        #pragma unroll
        for (int c4 = 0; c4 < 16; ++c4) {
            float4 a = ek[c4];
            d0 = fmaf(a.x, zr[4 * c4 + 0], d0);
            d1 = fmaf(a.y, zr[4 * c4 + 1], d1);
            d2 = fmaf(a.z, zr[4 * c4 + 2], d2);
            d3 = fmaf(a.w, zr[4 * c4 + 3], d3);
        }
        float dot  = (d0 + d1) + (d2 + d3);
        float dist = fmaf(-2.0f, dot, e2s[k0 + kk]);
        if (dist < best) { best = dist; bi = k0 + kk; }
    }
    wmin[wid][i] = best; widx[wid][i] = bi;
    __syncthreads();
    if (t < 64) {
        float m = wmin[0][t]; int ix = widx[0][t];
        #pragma unroll
        for (int w = 1; w < 4; ++w) {
            float v = wmin[w][t]; int x = widx[w][t];
            if (v < m) { m = v; ix = x; }
        }
        rowidx[t] = ix;
    }
    __syncthreads();

    float lsum = 0.f;
    const size_t base = (size_t)blk * 4096;
    float* oflat = out + base;
    #pragma unroll
    for (int j = 0; j < 16; ++j) {
        int f  = t + 256 * j;
        int nl = f >> 6, d = f & 63;
        int k  = rowidx[nl];
        float qv = E[(size_t)k * 64 + d];
        float zf = zs[d][nl];
        float df = qv - zf;
        lsum += df * df;
        oflat[f] = qv;
    }
    #pragma unroll
    for (int off = 32; off >= 1; off >>= 1) lsum += __shfl_down(lsum, off, 64);
    if (i == 0) wsum[wid] = lsum;
    __syncthreads();
    if (t == 0) {
        float s = (wsum[0] + wsum[1]) + (wsum[2] + wsum[3]);
        if (partial) partial[blk] = s;
        else         atomicAdd(&out[NDTOT + 1], s);
    }
}

__global__ __launch_bounds__(256) void vq_fin(const float* __restrict__ partial,
                                              float* __restrict__ out, int use_ws) {
    if (use_ws) {
        __shared__ float ps[256];
        float s = 0.f;
        for (int q = threadIdx.x; q < KCB; q += 256) s += partial[q];
        ps[threadIdx.x] = s;
        __syncthreads();
        for (int st = 128; st >= 1; st >>= 1) {
            if (threadIdx.x < st) ps[threadIdx.x] += ps[threadIdx.x + st];
            __syncthreads();
        }
        if (threadIdx.x == 0) {
            float mse = ps[0] / (float)NDTOT;
            out[NDTOT]     = 0.25f * mse;   // commitment_loss
            out[NDTOT + 1] = mse;           // codebook_loss
        }
    } else {
        if (threadIdx.x == 0) {
            float mse = out[NDTOT + 1] / (float)NDTOT;
            out[NDTOT]     = 0.25f * mse;
            out[NDTOT + 1] = mse;
        }
    }
}

extern "C" void kernel_launch(void* const* d_in, const int* in_sizes, int n_in,
                              void* d_out, int out_size, void* d_ws, size_t ws_size,
                              hipStream_t stream) {
    const float* z = (const float*)d_in[0];
    const float* E = (const float*)d_in[1];
    float* out = (float*)d_out;

    const size_t EBF_BYTES = (size_t)KCB * 64 * 2;          // 131072
    const size_t need = EBF_BYTES + 4096 + 4096;            // Ebf + he2b + partial

    if (ws_size >= need) {
        unsigned* EbfU = (unsigned*)d_ws;
        short* Ebf  = (short*)d_ws;
        float* he2b = (float*)((char*)d_ws + EBF_BYTES);
        float* partial = (float*)((char*)d_ws + EBF_BYTES + 4096);
        hipLaunchKernelGGL(vq_prep, dim3(4), dim3(256), 0, stream, E, EbfU, he2b);
        hipLaunchKernelGGL(vq_mfma, dim3(1024), dim3(256), 0, stream,
                           z, E, Ebf, he2b, out, partial);
        hipLaunchKernelGGL(vq_fin, dim3(1), dim3(256), 0, stream, partial, out, 1);
    } else {
        float* partial = (ws_size >= KCB * sizeof(float)) ? (float*)d_ws : nullptr;
        int use_ws = (partial != nullptr) ? 1 : 0;
        hipLaunchKernelGGL(vq_init, dim3(1), dim3(64), 0, stream, out);
        hipLaunchKernelGGL(vq_main_fp32, dim3(1024), dim3(256), 0, stream, z, E, out, partial);
        hipLaunchKernelGGL(vq_fin, dim3(1), dim3(256), 0, stream, partial, out, use_ws);
    }
}

// Round 4
// 56.169 us; speedup vs baseline: 2.1846x; 2.1846x over previous
//
#include <hip/hip_runtime.h>

// Problem constants (B=16, C=64, H=64, W=64, K=1024, D=64)
#define HWSZ   4096
#define CCH    64
#define KCB    1024
#define NROW   65536
#define NDTOT  4194304

typedef __attribute__((ext_vector_type(8))) short short8;
typedef __attribute__((ext_vector_type(4))) float f32x4;

__device__ __forceinline__ unsigned short f2bf_rn(float x) {
    union { float f; unsigned u; } v; v.f = x;
    unsigned r = (v.u + 0x7fffu + ((v.u >> 16) & 1u)) >> 16;
    return (unsigned short)r;
}

// ---------- prep: E -> bf16 rows + he2b[k] = 1.0 + 0.5*||e_k||^2 ----------
__global__ __launch_bounds__(256) void vq_prep(const float* __restrict__ E,
                                               unsigned* __restrict__ Ebf,
                                               float* __restrict__ he2b) {
    int k = blockIdx.x * 256 + threadIdx.x;   // 0..1023
    const float4* ep = (const float4*)(E + (size_t)k * 64);
    float s = 0.f;
    #pragma unroll
    for (int c4 = 0; c4 < 16; ++c4) {
        float4 a = ep[c4];
        s += a.x * a.x + a.y * a.y + a.z * a.z + a.w * a.w;
        Ebf[(size_t)k * 32 + 2 * c4 + 0] = (unsigned)f2bf_rn(a.x) | ((unsigned)f2bf_rn(a.y) << 16);
        Ebf[(size_t)k * 32 + 2 * c4 + 1] = (unsigned)f2bf_rn(a.z) | ((unsigned)f2bf_rn(a.w) << 16);
    }
    he2b[k] = 1.0f + 0.5f * s;
}

// ---------- main: 512 threads / 8 waves; wave = (code-quarter, row-half) ----------
__global__ __launch_bounds__(512, 2) void vq_mfma(const float* __restrict__ z,
                                                  const float* __restrict__ E,
                                                  const short* __restrict__ Ebf,
                                                  const float* __restrict__ he2g,
                                                  float* __restrict__ out,
                                                  float* __restrict__ partial) {
    __shared__ float zs[64][65];       // zs[c][i] = z_flat[n0+i][c]
    __shared__ float he2s[KCB];
    __shared__ unsigned wpack[8][64];
    __shared__ int   rowidx[64];
    __shared__ float wsum[8];

    const int t   = threadIdx.x;       // 0..511
    const int blk = blockIdx.x;        // 0..1023
    const int n0  = blk << 6;
    const int bb  = n0 >> 12;
    const int hw0 = n0 & 4095;
    const float* zb = z + (size_t)bb * CCH * HWSZ + hw0;

    // stage z tile: float4 global loads (coalesced), scalar LDS stores
    #pragma unroll
    for (int q2 = 0; q2 < 2; ++q2) {
        int fi = q2 * 512 + t;             // 1024 float4 slots
        int c = fi >> 4, s4 = fi & 15;
        float4 v = *(const float4*)(zb + (size_t)c * HWSZ + s4 * 4);
        zs[c][s4 * 4 + 0] = v.x; zs[c][s4 * 4 + 1] = v.y;
        zs[c][s4 * 4 + 2] = v.z; zs[c][s4 * 4 + 3] = v.w;
    }
    #pragma unroll
    for (int q2 = 0; q2 < 2; ++q2) he2s[q2 * 512 + t] = he2g[q2 * 512 + t];
    __syncthreads();

    const int wid  = t >> 6;           // 0..7
    const int lane = t & 63;
    const int col  = lane & 15;
    const int g    = lane >> 4;
    const int q    = wid & 3;          // code quarter
    const int h    = wid >> 2;         // row half (rows h*32 .. h*32+31)

    // A-frags for 2 row-tiles: -z, bf16 by truncation + sign flip
    short8 af[2][2];
    #pragma unroll
    for (int rtl = 0; rtl < 2; ++rtl) {
        const int i = (h * 2 + rtl) * 16 + col;
        #pragma unroll
        for (int ch = 0; ch < 2; ++ch) {
            short8 a;
            #pragma unroll
            for (int j = 0; j < 8; ++j) {
                union { float f; unsigned u; } v;
                v.f = zs[ch * 32 + g * 8 + j][i];
                a[j] = (short)((v.u >> 16) ^ 0x8000u);
            }
            af[rtl][ch] = a;
        }
    }

    float pk[2][4];                    // running packed (score|idx) minima
    #pragma unroll
    for (int rtl = 0; rtl < 2; ++rtl)
        #pragma unroll
        for (int r = 0; r < 4; ++r) pk[rtl][r] = 3.0e38f;

    // B stream: wave's 256-code quarter, 2-deep prefetch
    const short* pB = Ebf + (size_t)(q * 256 + col) * 64 + g * 8;
    short8 c0 = *(const short8*)(pB);
    short8 c1 = *(const short8*)(pB + 32);
    short8 nx0 = *(const short8*)(pB + 1024);
    short8 nx1 = *(const short8*)(pB + 1024 + 32);

    #pragma unroll
    for (int ct = 0; ct < 16; ++ct) {
        short8 f0 = c0, f1 = c1;
        if (ct < 14) {
            f0 = *(const short8*)(pB + (size_t)(ct + 2) * 1024);
            f1 = *(const short8*)(pB + (size_t)(ct + 2) * 1024 + 32);
        }
        const int code = q * 256 + ct * 16 + col;       // < 1024, fits 10 bits
        const float hb = he2s[code];
        f32x4 hv = {hb, hb, hb, hb};
        #pragma unroll
        for (int rtl = 0; rtl < 2; ++rtl) {
            f32x4 acc = __builtin_amdgcn_mfma_f32_16x16x32_bf16(af[rtl][0], c0, hv, 0, 0, 0);
            acc = __builtin_amdgcn_mfma_f32_16x16x32_bf16(af[rtl][1], c1, acc, 0, 0, 0);
            #pragma unroll
            for (int r = 0; r < 4; ++r) {
                union { float f; unsigned u; } m; m.f = acc[r];  // 1 + 0.5||e||^2 - z.e  (>0)
                m.u = (m.u & 0xFFFFFC00u) | (unsigned)code;      // v_and_or_b32
                pk[rtl][r] = fminf(pk[rtl][r], m.f);             // float-min == uint-min (>0)
            }
        }
        c0 = nx0; c1 = nx1; nx0 = f0; nx1 = f1;
    }

    // reduce across the 16 code-columns (lanes within each 16-group)
    #pragma unroll
    for (int rtl = 0; rtl < 2; ++rtl) {
        #pragma unroll
        for (int r = 0; r < 4; ++r) {
            float d = pk[rtl][r];
            #pragma unroll
            for (int mask = 1; mask < 16; mask <<= 1)
                d = fminf(d, __shfl_xor(d, mask, 64));
            if (col == 0) {
                union { float f; unsigned u; } b; b.f = d;
                wpack[wid][(h * 2 + rtl) * 16 + g * 4 + r] = b.u;
            }
        }
    }
    __syncthreads();

    if (t < 64) {   // combine the 4 quarter-waves covering this row's half
        int wb = (t >> 5) * 4;
        unsigned u0 = wpack[wb + 0][t], u1 = wpack[wb + 1][t];
        unsigned u2 = wpack[wb + 2][t], u3 = wpack[wb + 3][t];
        unsigned m01 = u0 < u1 ? u0 : u1;
        unsigned m23 = u2 < u3 ? u2 : u3;
        unsigned m = m01 < m23 ? m01 : m23;
        rowidx[t] = (int)(m & 1023u);
    }
    __syncthreads();

    // ---- output = E rows (== z + (q - z) to 1 ulp), float4 stores + loss ----
    float lsum = 0.f;
    const int d0i = (t & 15) * 4;
    const int r0  = t >> 4;                  // 0..31
    float* ob = out + (size_t)n0 * 64;
    #pragma unroll
    for (int jj = 0; jj < 2; ++jj) {
        int nl = r0 + 32 * jj;
        int k  = rowidx[nl];                 // uniform per 16-lane group
        float4 qv = *(const float4*)(E + (size_t)k * 64 + d0i);
        float z0 = zs[d0i + 0][nl], z1 = zs[d0i + 1][nl];
        float z2 = zs[d0i + 2][nl], z3 = zs[d0i + 3][nl];
        float e0 = qv.x - z0, e1 = qv.y - z1, e2 = qv.z - z2, e3 = qv.w - z3;
        lsum += e0 * e0 + e1 * e1 + e2 * e2 + e3 * e3;
        *(float4*)(ob + (size_t)nl * 64 + d0i) = qv;
    }

    #pragma unroll
    for (int off = 32; off >= 1; off >>= 1) lsum += __shfl_down(lsum, off, 64);
    if (lane == 0) wsum[wid] = lsum;
    __syncthreads();
    if (t == 0) {
        float s = ((wsum[0] + wsum[1]) + (wsum[2] + wsum[3]))
                + ((wsum[4] + wsum[5]) + (wsum[6] + wsum[7]));
        partial[blk] = s;
    }
}

// ---------- fallback fp32 path (round-1, correctness-proven) ----------
__global__ __launch_bounds__(64) void vq_init(float* out) {
    if (threadIdx.x == 0) { out[NDTOT] = 0.0f; out[NDTOT + 1] = 0.0f; }
}

__global__ __launch_bounds__(256, 4) void vq_main_fp32(const float* __restrict__ z,
                                                       const float* __restrict__ E,
                                                       float* __restrict__ out,
                                                       float* __restrict__ partial) {
    __shared__ float zs[64][65];
    __shared__ float e2s[KCB];
    __shared__ float wmin[4][64];
    __shared__ int   widx[4][64];
    __shared__ int   rowidx[64];
    __shared__ float wsum[4];

    const int t   = threadIdx.x;
    const int blk = blockIdx.x;
    const int n0  = blk << 6;
    const int bb  = n0 >> 12;
    const int hw0 = n0 & 4095;
    const float* zb = z + (size_t)bb * CCH * HWSZ + hw0;

    #pragma unroll
    for (int j = 0; j < 16; ++j) {
        int f = t + 256 * j;
        int c = f >> 6, i = f & 63;
        zs[c][i] = zb[(size_t)c * HWSZ + i];
    }
    for (int qq = t; qq < KCB; qq += 256) {
        const float4* ep = (const float4*)(E + (size_t)qq * 64);
        float s0 = 0.f;
        #pragma unroll
        for (int c4 = 0; c4 < 16; ++c4) {
            float4 a = ep[c4];
            s0 += a.x * a.x + a.y * a.y + a.z * a.z + a.w * a.w;
        }
        e2s[qq] = s0;
    }
    __syncthreads();

    const int i   = t & 63;
    const int wid = t >> 6;
    float zr[64];
    #pragma unroll
    for (int c = 0; c < 64; ++c) zr[c] = zs[c][i];

    float best = 3.4e38f;
    int   bi = 0;
    const int k0 = wid << 8;
    const float* Ew = E + (size_t)k0 * 64;
    for (int kk = 0; kk < 256; ++kk) {
        const float4* ek = (const float4*)(Ew + (size_t)kk * 64);
        float d0 = 0.f, d1 = 0.f, d2 = 0.f, d3 = 0.f;
        #pragma unroll
        for (int c4 = 0; c4 < 16; ++c4) {
            float4 a = ek[c4];
            d0 = fmaf(a.x, zr[4 * c4 + 0], d0);
            d1 = fmaf(a.y, zr[4 * c4 + 1], d1);
            d2 = fmaf(a.z, zr[4 * c4 + 2], d2);
            d3 = fmaf(a.w, zr[4 * c4 + 3], d3);
        }
        float dot  = (d0 + d1) + (d2 + d3);
        float dist = fmaf(-2.0f, dot, e2s[k0 + kk]);
        if (dist < best) { best = dist; bi = k0 + kk; }
    }
    wmin[wid][i] = best; widx[wid][i] = bi;
    __syncthreads();
    if (t < 64) {
        float m = wmin[0][t]; int ix = widx[0][t];
        #pragma unroll
        for (int w = 1; w < 4; ++w) {
            float v = wmin[w][t]; int x = widx[w][t];
            if (v < m) { m = v; ix = x; }
        }
        rowidx[t] = ix;
    }
    __syncthreads();

    float lsum = 0.f;
    const size_t base = (size_t)blk * 4096;
    float* oflat = out + base;
    #pragma unroll
    for (int j = 0; j < 16; ++j) {
        int f  = t + 256 * j;
        int nl = f >> 6, d = f & 63;
        int k  = rowidx[nl];
        float qv = E[(size_t)k * 64 + d];
        float zf = zs[d][nl];
        float df = qv - zf;
        lsum += df * df;
        oflat[f] = qv;
    }
    #pragma unroll
    for (int off = 32; off >= 1; off >>= 1) lsum += __shfl_down(lsum, off, 64);
    if (i == 0) wsum[wid] = lsum;
    __syncthreads();
    if (t == 0) {
        float s = (wsum[0] + wsum[1]) + (wsum[2] + wsum[3]);
        if (partial) partial[blk] = s;
        else         atomicAdd(&out[NDTOT + 1], s);
    }
}

__global__ __launch_bounds__(256) void vq_fin(const float* __restrict__ partial,
                                              float* __restrict__ out, int use_ws) {
    if (use_ws) {
        __shared__ float ps[256];
        float s = 0.f;
        for (int qq = threadIdx.x; qq < KCB; qq += 256) s += partial[qq];
        ps[threadIdx.x] = s;
        __syncthreads();
        for (int st = 128; st >= 1; st >>= 1) {
            if (threadIdx.x < st) ps[threadIdx.x] += ps[threadIdx.x + st];
            __syncthreads();
        }
        if (threadIdx.x == 0) {
            float mse = ps[0] / (float)NDTOT;
            out[NDTOT]     = 0.25f * mse;   // commitment_loss
            out[NDTOT + 1] = mse;           // codebook_loss
        }
    } else {
        if (threadIdx.x == 0) {
            float mse = out[NDTOT + 1] / (float)NDTOT;
            out[NDTOT]     = 0.25f * mse;
            out[NDTOT + 1] = mse;
        }
    }
}

extern "C" void kernel_launch(void* const* d_in, const int* in_sizes, int n_in,
                              void* d_out, int out_size, void* d_ws, size_t ws_size,
                              hipStream_t stream) {
    const float* z = (const float*)d_in[0];
    const float* E = (const float*)d_in[1];
    float* out = (float*)d_out;

    const size_t EBF_BYTES = (size_t)KCB * 64 * 2;          // 131072
    const size_t need = EBF_BYTES + 4096 + 4096;            // Ebf + he2b + partial

    if (ws_size >= need) {
        unsigned* EbfU = (unsigned*)d_ws;
        short* Ebf  = (short*)d_ws;
        float* he2b = (float*)((char*)d_ws + EBF_BYTES);
        float* partial = (float*)((char*)d_ws + EBF_BYTES + 4096);
        hipLaunchKernelGGL(vq_prep, dim3(4), dim3(256), 0, stream, E, EbfU, he2b);
        hipLaunchKernelGGL(vq_mfma, dim3(1024), dim3(512), 0, stream,
                           z, E, Ebf, he2b, out, partial);
        hipLaunchKernelGGL(vq_fin, dim3(1), dim3(256), 0, stream, partial, out, 1);
    } else {
        float* partial = (ws_size >= KCB * sizeof(float)) ? (float*)d_ws : nullptr;
        int use_ws = (partial != nullptr) ? 1 : 0;
        hipLaunchKernelGGL(vq_init, dim3(1), dim3(64), 0, stream, out);
        hipLaunchKernelGGL(vq_main_fp32, dim3(1024), dim3(256), 0, stream, z, E, out, partial);
        hipLaunchKernelGGL(vq_fin, dim3(1), dim3(256), 0, stream, partial, out, use_ws);
    }
}